// Round 1
// baseline (28.416 us; speedup 1.0000x reference)
//
#include <hip/hip_runtime.h>

#define NSAMP 64
#define ELEMS (512 * 512)      // per-sample elements = 262144
#define NBLK  32               // blocks per sample
#define TPB   256

// ---------------- Kernel 1: per-block partial reductions ----------------
// grid = NSAMP * NBLK, block = TPB. Each block reduces ELEMS/NBLK = 8192
// elements of one sample: pg = sum(s*m), pp = sum(s*s), gg = sum(m*m),
// sm = sum(s), where s = sigmoid(seg). Writes 4 floats per block to ws.
__global__ __launch_bounds__(TPB) void partials_kernel(
    const float* __restrict__ seg, const float* __restrict__ msk,
    float* __restrict__ ws)
{
    const int b    = blockIdx.x / NBLK;
    const int blk  = blockIdx.x % NBLK;
    const int per_block = ELEMS / NBLK;                   // 8192
    const size_t base = (size_t)b * ELEMS + (size_t)blk * per_block;
    const float4* s4 = (const float4*)(seg + base);
    const float4* m4 = (const float4*)(msk + base);
    const int n4 = per_block / 4;                         // 2048

    float pg = 0.f, pp = 0.f, gg = 0.f, sm = 0.f;

    for (int i = threadIdx.x; i < n4; i += TPB) {
        float4 x = s4[i];
        float4 m = m4[i];
        {
            float s = 1.0f / (1.0f + __expf(-x.x));
            pg = fmaf(s, m.x, pg); pp = fmaf(s, s, pp);
            gg = fmaf(m.x, m.x, gg); sm += s;
        }
        {
            float s = 1.0f / (1.0f + __expf(-x.y));
            pg = fmaf(s, m.y, pg); pp = fmaf(s, s, pp);
            gg = fmaf(m.y, m.y, gg); sm += s;
        }
        {
            float s = 1.0f / (1.0f + __expf(-x.z));
            pg = fmaf(s, m.z, pg); pp = fmaf(s, s, pp);
            gg = fmaf(m.z, m.z, gg); sm += s;
        }
        {
            float s = 1.0f / (1.0f + __expf(-x.w));
            pg = fmaf(s, m.w, pg); pp = fmaf(s, s, pp);
            gg = fmaf(m.w, m.w, gg); sm += s;
        }
    }

    // wave (64-lane) reduction
    #pragma unroll
    for (int o = 32; o; o >>= 1) {
        pg += __shfl_down(pg, o);
        pp += __shfl_down(pp, o);
        gg += __shfl_down(gg, o);
        sm += __shfl_down(sm, o);
    }

    // cross-wave via LDS (TPB/64 = 4 waves)
    __shared__ float red[TPB / 64][4];
    const int lane = threadIdx.x & 63;
    const int wid  = threadIdx.x >> 6;
    if (lane == 0) {
        red[wid][0] = pg; red[wid][1] = pp;
        red[wid][2] = gg; red[wid][3] = sm;
    }
    __syncthreads();
    if (threadIdx.x == 0) {
        float a = 0.f, c = 0.f, d = 0.f, e = 0.f;
        #pragma unroll
        for (int w = 0; w < TPB / 64; ++w) {
            a += red[w][0]; c += red[w][1];
            d += red[w][2]; e += red[w][3];
        }
        float* o = ws + (size_t)blockIdx.x * 4;
        o[0] = a; o[1] = c; o[2] = d; o[3] = e;
    }
}

// ---------------- Kernel 2: finalize both losses ----------------
// One wave (64 threads), thread b handles sample b.
__global__ __launch_bounds__(64) void final_kernel(
    const float* __restrict__ pc, const int* __restrict__ labels,
    const float* __restrict__ ws, float* __restrict__ out)
{
    const int b = threadIdx.x;    // 0..63 == sample index

    float pg = 0.f, pp = 0.f, gg = 0.f, sm = 0.f;
    for (int i = 0; i < NBLK; ++i) {
        const float* w = ws + ((size_t)b * NBLK + i) * 4;
        pg += w[0]; pp += w[1]; gg += w[2]; sm += w[3];
    }

    float p   = pc[b];
    float lab = (float)labels[b];

    // classification BCE term
    const float eps = 1e-7f;
    float pcc = fminf(fmaxf(p, eps), 1.f - eps);
    float bce = -(lab * logf(pcc) + (1.f - lab) * logf(1.f - pcc));

    // dice
    float dice_pos = (2.f * pg + 1e-5f) / (pp + gg + 1e-5f);
    float dice_neg = 25.f / (sm + 25.f);
    float dice = (lab == 1.f) ? dice_pos : dice_neg;

    float sel  = (p >= 0.5f) ? 1.f : 0.f;
    float nsel = sel;
    float dsum = sel * dice;

    #pragma unroll
    for (int o = 32; o; o >>= 1) {
        bce  += __shfl_down(bce, o);
        nsel += __shfl_down(nsel, o);
        dsum += __shfl_down(dsum, o);
    }

    if (b == 0) {
        out[0] = bce * (1.0f / 64.0f);
        out[1] = (nsel > 0.f) ? (nsel - dsum) / fmaxf(nsel, 1.f) : 1e-4f;
    }
}

extern "C" void kernel_launch(void* const* d_in, const int* in_sizes, int n_in,
                              void* d_out, int out_size, void* d_ws, size_t ws_size,
                              hipStream_t stream) {
    const float* predict_cls = (const float*)d_in[0];   // [64]
    const float* predict_seg = (const float*)d_in[1];   // [64,1,512,512]
    const int*   labels      = (const int*)d_in[2];     // [64]
    const float* masks       = (const float*)d_in[3];   // [64,1,512,512]
    float* out = (float*)d_out;                          // [2] = (cls_loss, seg_loss)
    float* ws  = (float*)d_ws;                           // NSAMP*NBLK*4 floats = 32 KiB

    partials_kernel<<<NSAMP * NBLK, TPB, 0, stream>>>(predict_seg, masks, ws);
    final_kernel<<<1, 64, 0, stream>>>(predict_cls, labels, ws, out);
}